// Round 11
// baseline (929.535 us; speedup 1.0000x reference)
//
#include <hip/hip_runtime.h>
#include <hip/hip_cooperative_groups.h>

#define I_DIM 1025
#define J_DIM 2048
#define K_B 8
#define IC 33            // i-chunks of 32 (last has 1)
#define EPSF 1e-20f

namespace cg = cooperative_groups;

// ---------------- helpers ----------------

__device__ __forceinline__ int rev4i(int x) {
  return ((x & 1) << 3) | ((x & 2) << 1) | ((x & 4) >> 1) | ((x & 8) >> 3);
}
__device__ __forceinline__ int rev3i(int x) {
  return ((x & 1) << 2) | (x & 2) | ((x & 4) >> 2);
}

// value-halving butterfly: 16 vals over 64 lanes in 17 shuffles.
// Post: vals[0] of lane l (l<16) holds total of value rev4i(l).
__device__ __forceinline__ void foldReduce16(float* vals, int lane) {
  #pragma unroll
  for (int step = 0; step < 4; ++step) {
    const int nv = 8 >> step;           // 8,4,2,1
    const int bit = (lane >> step) & 1;
    #pragma unroll
    for (int q = 0; q < nv; ++q) {
      float a = vals[q], b = vals[q + nv];
      float send = bit ? a : b;
      float keep = bit ? b : a;
      vals[q] = keep + __shfl_xor(send, 1 << step);
    }
  }
  vals[0] += __shfl_xor(vals[0], 16);
  vals[0] += __shfl_xor(vals[0], 32);
}

// 8 vals over 64 lanes. Post: lane l (l<8) holds total of value rev3i(l).
__device__ __forceinline__ void foldReduce8(float* vals, int lane) {
  #pragma unroll
  for (int step = 0; step < 3; ++step) {
    const int nv = 4 >> step;           // 4,2,1
    const int bit = (lane >> step) & 1;
    #pragma unroll
    for (int q = 0; q < nv; ++q) {
      float a = vals[q], b = vals[q + nv];
      float send = bit ? a : b;
      float keep = bit ? b : a;
      vals[q] = keep + __shfl_xor(send, 1 << step);
    }
  }
  vals[0] += __shfl_xor(vals[0], 8);
  vals[0] += __shfl_xor(vals[0], 16);
  vals[0] += __shfl_xor(vals[0], 32);
}

__device__ __forceinline__ float2 cmul(float2 a, float2 b) {
  return make_float2(a.x*b.x - a.y*b.y, a.x*b.y + a.y*b.x);
}
__device__ __forceinline__ float2 cadd(float2 a, float2 b) {
  return make_float2(a.x + b.x, a.y + b.y);
}
__device__ __forceinline__ float2 csub(float2 a, float2 b) {
  return make_float2(a.x - b.x, a.y - b.y);
}
__device__ __forceinline__ float2 cdiv(float2 a, float2 b) {
  float s = 1.0f / (b.x*b.x + b.y*b.y);
  return make_float2((a.x*b.x + a.y*b.y)*s, (a.y*b.x - a.x*b.y)*s);
}

// ---------------- transpose X -> Xq[i][j]=(re0,im0,re1,im1), + init T/V/W ----
// T: [n][i][k]; V: [n][j][k] (float4-pair per j); W: [i][n][m][c]
__global__ __launch_bounds__(256) void k_tr_init(
    const float* __restrict__ X, float4* __restrict__ Xq,
    const float* __restrict__ T0, const float* __restrict__ V0,
    float* __restrict__ T, float* __restrict__ V, float* __restrict__ W)
{
  const int tx = threadIdx.x, ty = threadIdx.y;  // (32, 8)
  const int lt = ty * 32 + tx;
  const int bid = blockIdx.y * 33 + blockIdx.x;
  int t = bid * 256 + lt;
  if (t < 2 * K_B * J_DIM) {               // V: 32768, [n][j][k]
    int n = t >> 14;
    int r = t & 16383;
    int j = r >> 3, k = r & 7;
    V[t] = V0[(k * J_DIM + j) * 2 + n];
  }
  if (t < 2 * I_DIM * K_B) {               // T: 16400
    int n = t / (I_DIM * K_B);
    int r = t % (I_DIM * K_B);
    int i = r / K_B, k = r % K_B;
    T[t] = T0[(i * K_B + k) * 2 + n];
  }
  if (t < I_DIM * 8) {                     // W: 8200
    int u = t & 7;
    int c = u & 1, m = (u >> 1) & 1, n = u >> 2;
    W[t] = (n == m && c == 0) ? 1.0f : 0.0f;
  }
  // ---- transpose ----
  __shared__ float t0r[32][33], t0i[32][33], t1r[32][33], t1i[32][33];
  const int i0 = blockIdx.x * 32, j0 = blockIdx.y * 32;
  const float2* __restrict__ X2 = (const float2*)X;
  #pragma unroll
  for (int jj = 0; jj < 4; ++jj) {
    int jl = ty + jj * 8;
    int i = i0 + tx;
    if (i < I_DIM) {
      float2 v0 = X2[(size_t)(0 * J_DIM + j0 + jl) * I_DIM + i];
      float2 v1 = X2[(size_t)(1 * J_DIM + j0 + jl) * I_DIM + i];
      t0r[jl][tx] = v0.x; t0i[jl][tx] = v0.y;
      t1r[jl][tx] = v1.x; t1i[jl][tx] = v1.y;
    }
  }
  __syncthreads();
  #pragma unroll
  for (int ii = 0; ii < 4; ++ii) {
    int il = ty + ii * 8;
    int i = i0 + il;
    if (i < I_DIM) {
      Xq[(size_t)i * J_DIM + j0 + tx] =
        make_float4(t0r[tx][il], t0i[tx][il], t1r[tx][il], t1i[tx][il]);
    }
  }
}

// ---------------- NMF T-step body (xs preloaded by caller) -------------------
template<int N>
__device__ __forceinline__ void nmfT_src(
    const float4* xs, int i, int tid,
    float* __restrict__ T, const float* __restrict__ V,
    const float* __restrict__ W, float* __restrict__ YdR)
{
  const float4 w = ((const float4*)W)[i * 2 + N];
  const int trow = (N * I_DIM + i) * K_B;
  float t[K_B];
  #pragma unroll
  for (int k = 0; k < K_B; ++k) t[k] = T[trow + k];

  float num[K_B], den[K_B];
  #pragma unroll
  for (int k = 0; k < K_B; ++k) { num[k] = 0.f; den[k] = 0.f; }

  const float4* __restrict__ V4 = (const float4*)V;
  #pragma unroll
  for (int u = 0; u < 8; ++u) {
    int j = u * 256 + tid;
    float4 va = V4[(N * J_DIM + j) * 2 + 0];
    float4 vb = V4[(N * J_DIM + j) * 2 + 1];
    float v[K_B] = {va.x, va.y, va.z, va.w, vb.x, vb.y, vb.z, vb.w};
    float rn = 0.f;
    #pragma unroll
    for (int k = 0; k < K_B; ++k) rn += t[k] * v[k];
    float4 x = xs[u];
    float yr = w.x * x.x - w.y * x.y + w.z * x.z - w.w * x.w;
    float yi = w.x * x.y + w.y * x.x + w.z * x.w + w.w * x.z;
    float rd = __builtin_amdgcn_rcpf(fabsf(rn) + EPSF);
    float ydr = (yr * yr + yi * yi) * rd * rd;
    YdR[(size_t)i * J_DIM + j] = ydr;
    #pragma unroll
    for (int k = 0; k < K_B; ++k) { num[k] += ydr * v[k]; den[k] += rd * v[k]; }
  }

  float vals[16];
  #pragma unroll
  for (int k = 0; k < K_B; ++k) { vals[k] = num[k]; vals[K_B + k] = den[k]; }
  const int wave = tid >> 6, lane = tid & 63;
  foldReduce16(vals, lane);
  __shared__ float redT[4][16];
  if (lane < 16) redT[wave][lane] = vals[0];   // slot l holds value rev4i(l)
  __syncthreads();
  if (tid < K_B) {
    int r = rev4i(tid);
    float nm = redT[0][r] + redT[1][r] + redT[2][r] + redT[3][r];
    float dn = redT[0][r+1] + redT[1][r+1] + redT[2][r+1] + redT[3][r+1];
    T[trow + tid] *= sqrtf(nm / (dn + EPSF));
  }
}

__device__ __forceinline__ void nmf_pair(
    const float4* xs, int i, int tid,
    float* __restrict__ T, const float* __restrict__ V,
    const float* __restrict__ W,
    float* __restrict__ Y0, float* __restrict__ Y1)
{
  nmfT_src<0>(xs, i, tid, T, V, W, Y0);
  __syncthreads();
  nmfT_src<1>(xs, i, tid, T, V, W, Y1);
  __syncthreads();          // protect redT reuse by a subsequent call
}

// ---------------- dual 2x2 solve epilogue (one thread) -----------------------
__device__ __forceinline__ void ip_solve_both(
    int i,
    float D000, float p0, float q0, float D110,
    float D001, float p1, float q1, float D111,
    float* __restrict__ W)
{
  float4 w0 = ((const float4*)W)[i * 2 + 0];
  float4 w1 = ((const float4*)W)[i * 2 + 1];
  float2 W00 = make_float2(w0.x, w0.y), W01 = make_float2(w0.z, w0.w);
  float2 W10 = make_float2(w1.x, w1.y), W11 = make_float2(w1.z, w1.w);
  {
    float D00 = D000 + EPSF, D11 = D110 + EPSF;
    float2 D01 = make_float2(p0, q0);
    float2 D10 = make_float2(p0, -q0);
    float2 A00 = cadd(make_float2(W00.x * D00, W00.y * D00), cmul(W01, D10));
    float2 A01 = cadd(cmul(W00, D01), make_float2(W01.x * D11, W01.y * D11));
    float2 A10 = cadd(make_float2(W10.x * D00, W10.y * D00), cmul(W11, D10));
    float2 A11 = cadd(cmul(W10, D01), make_float2(W11.x * D11, W11.y * D11));
    float2 det = csub(cmul(A00, A11), cmul(A01, A10));
    float2 b0 = cdiv(A11, det);
    float2 b1 = cdiv(make_float2(-A10.x, -A10.y), det);
    float2 Db0 = cadd(make_float2(D00 * b0.x, D00 * b0.y), cmul(D01, b1));
    float2 Db1 = cadd(cmul(D10, b0), make_float2(D11 * b1.x, D11 * b1.y));
    float ip = b0.x * Db0.x + b0.y * Db0.y + b1.x * Db1.x + b1.y * Db1.y;
    float inv = 1.0f / sqrtf(ip + EPSF);
    W00 = make_float2(b0.x * inv, -b0.y * inv);
    W01 = make_float2(b1.x * inv, -b1.y * inv);
  }
  {
    float D00 = D001 + EPSF, D11 = D111 + EPSF;
    float2 D01 = make_float2(p1, q1);
    float2 D10 = make_float2(p1, -q1);
    float2 A00 = cadd(make_float2(W00.x * D00, W00.y * D00), cmul(W01, D10));
    float2 A01 = cadd(cmul(W00, D01), make_float2(W01.x * D11, W01.y * D11));
    float2 A10 = cadd(make_float2(W10.x * D00, W10.y * D00), cmul(W11, D10));
    float2 A11 = cadd(cmul(W10, D01), make_float2(W11.x * D11, W11.y * D11));
    float2 det = csub(cmul(A00, A11), cmul(A01, A10));
    float2 b0 = cdiv(make_float2(-A01.x, -A01.y), det);
    float2 b1 = cdiv(A00, det);
    float2 Db0 = cadd(make_float2(D00 * b0.x, D00 * b0.y), cmul(D01, b1));
    float2 Db1 = cadd(cmul(D10, b0), make_float2(D11 * b1.x, D11 * b1.y));
    float ip = b0.x * Db0.x + b0.y * Db0.y + b1.x * Db1.x + b1.y * Db1.y;
    float inv = 1.0f / sqrtf(ip + EPSF);
    W10 = make_float2(b0.x * inv, -b0.y * inv);
    W11 = make_float2(b1.x * inv, -b1.y * inv);
  }
  ((float4*)W)[i * 2 + 0] = make_float4(W00.x, W00.y, W01.x, W01.y);
  ((float4*)W)[i * 2 + 1] = make_float4(W10.x, W10.y, W11.x, W11.y);
}

// ---------------- IP body, both sources (xs preloaded) -----------------------
__device__ __forceinline__ void ip_pair(
    const float4* xs, int i, int tid,
    const float* __restrict__ T, const float* __restrict__ V,
    float* __restrict__ W)
{
  float t0[K_B], t1[K_B];
  #pragma unroll
  for (int k = 0; k < K_B; ++k) {
    t0[k] = T[(0 * I_DIM + i) * K_B + k];
    t1[k] = T[(1 * I_DIM + i) * K_B + k];
  }
  const float4* __restrict__ V4 = (const float4*)V;
  float acc[8];
  #pragma unroll
  for (int q = 0; q < 8; ++q) acc[q] = 0.f;

  #pragma unroll
  for (int u = 0; u < 8; ++u) {
    int j = u * 256 + tid;
    float4 va0 = V4[(0 * J_DIM + j) * 2 + 0];
    float4 vb0 = V4[(0 * J_DIM + j) * 2 + 1];
    float4 va1 = V4[(1 * J_DIM + j) * 2 + 0];
    float4 vb1 = V4[(1 * J_DIM + j) * 2 + 1];
    float rn0 = t0[0]*va0.x + t0[1]*va0.y + t0[2]*va0.z + t0[3]*va0.w
              + t0[4]*vb0.x + t0[5]*vb0.y + t0[6]*vb0.z + t0[7]*vb0.w;
    float rn1 = t1[0]*va1.x + t1[1]*va1.y + t1[2]*va1.z + t1[3]*va1.w
              + t1[4]*vb1.x + t1[5]*vb1.y + t1[6]*vb1.z + t1[7]*vb1.w;
    float w0 = __builtin_amdgcn_rcpf(rn0 + EPSF);
    float w1 = __builtin_amdgcn_rcpf(rn1 + EPSF);
    float4 x = xs[u];
    float m00 = x.x * x.x + x.y * x.y;
    float m11 = x.z * x.z + x.w * x.w;
    float m01r = x.x * x.z + x.y * x.w;
    float m01i = x.y * x.z - x.x * x.w;
    acc[0] += m00 * w0; acc[1] += m01r * w0; acc[2] += m01i * w0; acc[3] += m11 * w0;
    acc[4] += m00 * w1; acc[5] += m01r * w1; acc[6] += m01i * w1; acc[7] += m11 * w1;
  }
  const int wave = tid >> 6, lane = tid & 63;
  foldReduce8(acc, lane);
  __shared__ float redI[4][8];
  if (lane < 8) redI[wave][lane] = acc[0];
  __syncthreads();
  if (tid == 0) {
    const float invJ = 1.0f / (float)J_DIM;
    float s[8];
    #pragma unroll
    for (int vv = 0; vv < 8; ++vv) {
      int r = rev3i(vv);
      s[vv] = (redI[0][r] + redI[1][r] + redI[2][r] + redI[3][r]) * invJ;
    }
    ip_solve_both(i, s[0], s[1], s[2], s[3], s[4], s[5], s[6], s[7], W);
  }
  __syncthreads();          // protect redI reuse by a subsequent call
}

// ---------------- V partials stage (vb in [0,528)) ---------------------------
__device__ __forceinline__ void part_stage(
    int vb, int tid,
    const float* __restrict__ T, const float* __restrict__ V,
    const float* __restrict__ Y0, const float* __restrict__ Y1,
    float* __restrict__ Pn0, float* __restrict__ Pd0,
    float* __restrict__ Pn1, float* __restrict__ Pd1)
{
  __shared__ float4 sT4[64];
  __syncthreads();                       // protect sT4 reuse across calls
  const int src = vb / 264;
  const int pb = vb % 264;
  const int jb = pb & 7, c = pb >> 3;
  const int i0 = c * 32;
  const int ni = min(32, I_DIM - i0);
  if (tid < ni * 2)
    sT4[tid] = ((const float4*)(T + (size_t)(src * I_DIM + i0) * K_B))[tid];
  __syncthreads();

  const float* __restrict__ YdR = src ? Y1 : Y0;
  float* __restrict__ Pn = src ? Pn1 : Pn0;
  float* __restrict__ Pd = src ? Pd1 : Pd0;
  const int j = jb * 256 + tid;
  const float4* __restrict__ V4 = (const float4*)V;
  float4 va = V4[(src * J_DIM + j) * 2 + 0];
  float4 vb4 = V4[(src * J_DIM + j) * 2 + 1];
  float v[K_B] = {va.x, va.y, va.z, va.w, vb4.x, vb4.y, vb4.z, vb4.w};
  float num[K_B], den[K_B];
  #pragma unroll
  for (int k = 0; k < K_B; ++k) { num[k] = 0.f; den[k] = 0.f; }

  if (ni == 32) {
    #pragma unroll
    for (int g = 0; g < 4; ++g) {
      float yd[8];
      #pragma unroll
      for (int q = 0; q < 8; ++q)
        yd[q] = YdR[(size_t)(i0 + g * 8 + q) * J_DIM + j];
      #pragma unroll
      for (int q = 0; q < 8; ++q) {
        const int ii = g * 8 + q;
        float4 ta = sT4[ii * 2], tb = sT4[ii * 2 + 1];
        float tk[K_B] = {ta.x, ta.y, ta.z, ta.w, tb.x, tb.y, tb.z, tb.w};
        float rn = 0.f;
        #pragma unroll
        for (int k = 0; k < K_B; ++k) rn += tk[k] * v[k];
        float rd2 = __builtin_amdgcn_rcpf(fabsf(rn) + EPSF);
        #pragma unroll
        for (int k = 0; k < K_B; ++k) {
          num[k] += tk[k] * yd[q];
          den[k] += tk[k] * rd2;
        }
      }
    }
  } else {
    for (int ii = 0; ii < ni; ++ii) {
      float ydr = YdR[(size_t)(i0 + ii) * J_DIM + j];
      float4 ta = sT4[ii * 2], tb = sT4[ii * 2 + 1];
      float tk[K_B] = {ta.x, ta.y, ta.z, ta.w, tb.x, tb.y, tb.z, tb.w};
      float rn = 0.f;
      #pragma unroll
      for (int k = 0; k < K_B; ++k) rn += tk[k] * v[k];
      float rd2 = __builtin_amdgcn_rcpf(fabsf(rn) + EPSF);
      #pragma unroll
      for (int k = 0; k < K_B; ++k) {
        num[k] += tk[k] * ydr;
        den[k] += tk[k] * rd2;
      }
    }
  }
  ((float4*)Pn)[((size_t)c * J_DIM + j) * 2 + 0] = make_float4(num[0], num[1], num[2], num[3]);
  ((float4*)Pn)[((size_t)c * J_DIM + j) * 2 + 1] = make_float4(num[4], num[5], num[6], num[7]);
  ((float4*)Pd)[((size_t)c * J_DIM + j) * 2 + 0] = make_float4(den[0], den[1], den[2], den[3]);
  ((float4*)Pd)[((size_t)c * J_DIM + j) * 2 + 1] = make_float4(den[4], den[5], den[6], den[7]);
}

// ---------------- V finalize stage (vb in [0,32)) ----------------------------
__device__ __forceinline__ void fin_stage(
    int vb, int tid, float* __restrict__ V,
    const float* __restrict__ Pn0, const float* __restrict__ Pd0,
    const float* __restrict__ Pn1, const float* __restrict__ Pd1)
{
  const int src = vb >> 4, fb = vb & 15;
  const float* __restrict__ Pn = src ? Pn1 : Pn0;
  const float* __restrict__ Pd = src ? Pd1 : Pd0;
  const int t4 = fb * 256 + tid;
  const float4* __restrict__ Pn4 = (const float4*)Pn;
  const float4* __restrict__ Pd4 = (const float4*)Pd;
  float4 nm = make_float4(0.f, 0.f, 0.f, 0.f);
  float4 dn = make_float4(0.f, 0.f, 0.f, 0.f);
  #pragma unroll
  for (int c = 0; c < IC; ++c) {
    float4 a = Pn4[(size_t)c * 4096 + t4];
    float4 bb = Pd4[(size_t)c * 4096 + t4];
    nm.x += a.x; nm.y += a.y; nm.z += a.z; nm.w += a.w;
    dn.x += bb.x; dn.y += bb.y; dn.z += bb.z; dn.w += bb.w;
  }
  float4* __restrict__ V4o = (float4*)(V + src * (K_B * J_DIM));
  float4 v = V4o[t4];
  v.x *= sqrtf(nm.x / (dn.x + EPSF));
  v.y *= sqrtf(nm.y / (dn.y + EPSF));
  v.z *= sqrtf(nm.z / (dn.z + EPSF));
  v.w *= sqrtf(nm.w / (dn.w + EPSF));
  V4o[t4] = v;
}

// ---------------- fallback standalone kernels (R9 structure) -----------------
__global__ __launch_bounds__(256) void k_nmf2(
    const float4* __restrict__ Xq, float* __restrict__ T,
    const float* __restrict__ V, const float* __restrict__ W,
    float* __restrict__ Y0, float* __restrict__ Y1)
{
  int b = blockIdx.x;
  int p, pop;
  if (b >= 2048) { p = 1024; pop = b - 2048; }
  else { pop = (b >> 3) & 1; p = ((b >> 4) << 3) | (b & 7); }
  float4 xs[8];
  #pragma unroll
  for (int u = 0; u < 8; ++u) xs[u] = Xq[(size_t)p * J_DIM + u * 256 + threadIdx.x];
  if (pop == 0)
    nmfT_src<0>(xs, p, threadIdx.x, T, V, W, Y0);
  else
    nmfT_src<1>(xs, p, threadIdx.x, T, V, W, Y1);
}

__global__ __launch_bounds__(256) void k_part2(
    const float* __restrict__ T, const float* __restrict__ V,
    const float* __restrict__ Y0, const float* __restrict__ Y1,
    float* __restrict__ Pn0, float* __restrict__ Pd0,
    float* __restrict__ Pn1, float* __restrict__ Pd1)
{
  part_stage(blockIdx.x, threadIdx.x, T, V, Y0, Y1, Pn0, Pd0, Pn1, Pd1);
}

__global__ __launch_bounds__(256) void k_fin2(
    float* __restrict__ V,
    const float* __restrict__ Pn0, const float* __restrict__ Pd0,
    const float* __restrict__ Pn1, const float* __restrict__ Pd1)
{
  fin_stage(blockIdx.x, threadIdx.x, V, Pn0, Pd0, Pn1, Pd1);
}

__global__ __launch_bounds__(256) void k_ip2(
    const float4* __restrict__ Xq, const float* __restrict__ T,
    const float* __restrict__ V, float* __restrict__ W)
{
  float4 xs[8];
  #pragma unroll
  for (int u = 0; u < 8; ++u)
    xs[u] = Xq[(size_t)blockIdx.x * J_DIM + u * 256 + threadIdx.x];
  ip_pair(xs, blockIdx.x, threadIdx.x, T, V, W);
}

__global__ __launch_bounds__(256) void k_out(
    const float* __restrict__ X, const float* __restrict__ W, float* __restrict__ out)
{
  const int j = blockIdx.x;
  const int i = blockIdx.y * 256 + threadIdx.x;
  if (i >= I_DIM) return;
  const float2* __restrict__ X2 = (const float2*)X;
  float2 x0 = X2[(size_t)(0 * J_DIM + j) * I_DIM + i];
  float2 x1 = X2[(size_t)(1 * J_DIM + j) * I_DIM + i];
  const float4* __restrict__ W4 = (const float4*)W;
  float4 w0 = W4[i * 2 + 0];
  float4 w1 = W4[i * 2 + 1];
  float2* __restrict__ O = (float2*)out;
  float yr = w0.x * x0.x - w0.y * x0.y + w0.z * x1.x - w0.w * x1.y;
  float yi = w0.x * x0.y + w0.y * x0.x + w0.z * x1.y + w0.w * x1.x;
  O[(size_t)(0 * J_DIM + j) * I_DIM + i] = make_float2(yr, yi);
  yr = w1.x * x0.x - w1.y * x0.y + w1.z * x1.x - w1.w * x1.y;
  yi = w1.x * x0.y + w1.y * x0.x + w1.z * x1.y + w1.w * x1.x;
  O[(size_t)(1 * J_DIM + j) * I_DIM + i] = make_float2(yr, yi);
}

// ---------------- persistent cooperative megakernel (grid-agnostic) ----------
__global__ void __launch_bounds__(256, 2) k_mega(
    const float4* __restrict__ Xq, const float* __restrict__ X,
    float* __restrict__ T, float* __restrict__ V, float* __restrict__ W,
    float* __restrict__ Y0, float* __restrict__ Y1,
    float* __restrict__ Pn0, float* __restrict__ Pd0,
    float* __restrict__ Pn1, float* __restrict__ Pd1,
    float* __restrict__ out)
{
  extern __shared__ float4 Xl[];   // 2048 float4 = 32 KB: this block's first row
  cg::grid_group gg = cg::this_grid();
  const int b = blockIdx.x;
  const int tid = threadIdx.x;
  const int G = gridDim.x;

  // cache own first row (row index == b) — threads read back only what they wrote
  #pragma unroll
  for (int u = 0; u < 8; ++u)
    Xl[u * 256 + tid] = Xq[(size_t)b * J_DIM + u * 256 + tid];

  for (int it = 0; it < 5; ++it) {
    // ---- nmf stage ----
    for (int r = b; r < I_DIM; r += G) {
      float4 xs[8];
      if (r == b) {
        #pragma unroll
        for (int u = 0; u < 8; ++u) xs[u] = Xl[u * 256 + tid];
      } else {
        #pragma unroll
        for (int u = 0; u < 8; ++u) xs[u] = Xq[(size_t)r * J_DIM + u * 256 + tid];
      }
      nmf_pair(xs, r, tid, T, V, W, Y0, Y1);
    }
    gg.sync();
    // ---- part stage ----
    for (int vb = b; vb < 528; vb += G)
      part_stage(vb, tid, T, V, Y0, Y1, Pn0, Pd0, Pn1, Pd1);
    gg.sync();
    // ---- fin stage ----
    for (int vb = b; vb < 32; vb += G)
      fin_stage(vb, tid, V, Pn0, Pd0, Pn1, Pd1);
    gg.sync();
    // ---- ip stage ----
    for (int r = b; r < I_DIM; r += G) {
      float4 xs[8];
      if (r == b) {
        #pragma unroll
        for (int u = 0; u < 8; ++u) xs[u] = Xl[u * 256 + tid];
      } else {
        #pragma unroll
        for (int u = 0; u < 8; ++u) xs[u] = Xq[(size_t)r * J_DIM + u * 256 + tid];
      }
      ip_pair(xs, r, tid, T, V, W);
    }
    gg.sync();
  }

  // ---- out stage: Y = W @ Xc, layout (N, J, I, 2) ----
  const float2* __restrict__ X2 = (const float2*)X;
  const float4* __restrict__ W4 = (const float4*)W;
  float2* __restrict__ O = (float2*)out;
  for (int vb = b; vb < 10240; vb += G) {
    int j = vb & 2047, iseg = vb >> 11;
    int i = iseg * 256 + tid;
    if (i < I_DIM) {
      float2 x0 = X2[(size_t)(0 * J_DIM + j) * I_DIM + i];
      float2 x1 = X2[(size_t)(1 * J_DIM + j) * I_DIM + i];
      float4 w0 = W4[i * 2 + 0];
      float4 w1 = W4[i * 2 + 1];
      float yr = w0.x * x0.x - w0.y * x0.y + w0.z * x1.x - w0.w * x1.y;
      float yi = w0.x * x0.y + w0.y * x0.x + w0.z * x1.y + w0.w * x1.x;
      O[(size_t)(0 * J_DIM + j) * I_DIM + i] = make_float2(yr, yi);
      yr = w1.x * x0.x - w1.y * x0.y + w1.z * x1.x - w1.w * x1.y;
      yi = w1.x * x0.y + w1.y * x0.x + w1.z * x1.y + w1.w * x1.x;
      O[(size_t)(1 * J_DIM + j) * I_DIM + i] = make_float2(yr, yi);
    }
  }
}

// ---------------- launch ----------------
extern "C" void kernel_launch(void* const* d_in, const int* in_sizes, int n_in,
                              void* d_out, int out_size, void* d_ws, size_t ws_size,
                              hipStream_t stream) {
  const float* X  = (const float*)d_in[0];   // (2, 2048, 1025, 2)
  const float* T0 = (const float*)d_in[1];   // (1025, 8, 2)
  const float* V0 = (const float*)d_in[2];   // (8, 2048, 2)
  float* ws = (float*)d_ws;
  // workspace layout (floats)
  float4* Xq  = (float4*)ws;           // 8396800 floats
  float* Y0   = ws + 8396800;          // 2099200
  float* Y1   = ws + 10496000;         // 2099200
  float* T    = ws + 12595200;         // 16400
  float* V    = ws + 12611600;         // 32768 ([n][j][k])
  float* W    = ws + 12644368;         // 8200
  float* Pn0  = ws + 12652568;         // 540672 ([c][j][k])
  float* Pd0  = ws + 13193240;         // 540672
  float* Pn1  = ws + 13733912;         // 540672
  float* Pd1  = ws + 14274584;         // 540672
  float* outp = (float*)d_out;

  k_tr_init<<<dim3(33, 64), dim3(32, 8), 0, stream>>>(X, Xq, T0, V0, T, V, W);

  // adaptive cooperative launch with checked fallback
  bool mega_ok = false;
  int occ = 0;
  hipError_t qerr = hipOccupancyMaxActiveBlocksPerMultiprocessor(
      &occ, k_mega, 256, (size_t)32768);
  if (qerr == hipSuccess && occ > 0) {
    int grid = occ * 256;              // 256 CUs on MI355X
    if (grid > 1024) grid = 1024;
    void* args[] = {(void*)&Xq, (void*)&X, (void*)&T, (void*)&V, (void*)&W,
                    (void*)&Y0, (void*)&Y1, (void*)&Pn0, (void*)&Pd0,
                    (void*)&Pn1, (void*)&Pd1, (void*)&outp};
    hipError_t lerr = hipLaunchCooperativeKernel(
        (const void*)k_mega, dim3(grid), dim3(256), args, 32768, stream);
    mega_ok = (lerr == hipSuccess);
    if (!mega_ok) (void)hipGetLastError();   // clear sticky error
  } else {
    (void)hipGetLastError();
  }

  if (!mega_ok) {
    // fallback: proven R9 path (~290 us)
    for (int it = 0; it < 5; ++it) {
      k_nmf2<<<2 * I_DIM, 256, 0, stream>>>(Xq, T, V, W, Y0, Y1);
      k_part2<<<528, 256, 0, stream>>>(T, V, Y0, Y1, Pn0, Pd0, Pn1, Pd1);
      k_fin2<<<32, 256, 0, stream>>>(V, Pn0, Pd0, Pn1, Pd1);
      k_ip2<<<I_DIM, 256, 0, stream>>>(Xq, T, V, W);
    }
    k_out<<<dim3(J_DIM, 5), 256, 0, stream>>>(X, W, outp);
  }
}

// Round 12
// 276.828 us; speedup vs baseline: 3.3578x; 3.3578x over previous
//
#include <hip/hip_runtime.h>

#define I_DIM 1025
#define J_DIM 2048
#define K_B 8
#define IC 33            // i-chunks of 32 (last has 1)
#define EPSF 1e-20f

// ---------------- helpers ----------------

__device__ __forceinline__ int rev4i(int x) {
  return ((x & 1) << 3) | ((x & 2) << 1) | ((x & 4) >> 1) | ((x & 8) >> 3);
}
__device__ __forceinline__ int rev3i(int x) {
  return ((x & 1) << 2) | (x & 2) | ((x & 4) >> 2);
}

// value-halving butterfly: 16 vals over 64 lanes in 17 shuffles.
// Post: vals[0] of lane l (l<16) holds total of value rev4i(l).
__device__ __forceinline__ void foldReduce16(float* vals, int lane) {
  #pragma unroll
  for (int step = 0; step < 4; ++step) {
    const int nv = 8 >> step;           // 8,4,2,1
    const int bit = (lane >> step) & 1;
    #pragma unroll
    for (int q = 0; q < nv; ++q) {
      float a = vals[q], b = vals[q + nv];
      float send = bit ? a : b;
      float keep = bit ? b : a;
      vals[q] = keep + __shfl_xor(send, 1 << step);
    }
  }
  vals[0] += __shfl_xor(vals[0], 16);
  vals[0] += __shfl_xor(vals[0], 32);
}

// 8 vals over 64 lanes. Post: lane l (l<8) holds total of value rev3i(l).
__device__ __forceinline__ void foldReduce8(float* vals, int lane) {
  #pragma unroll
  for (int step = 0; step < 3; ++step) {
    const int nv = 4 >> step;           // 4,2,1
    const int bit = (lane >> step) & 1;
    #pragma unroll
    for (int q = 0; q < nv; ++q) {
      float a = vals[q], b = vals[q + nv];
      float send = bit ? a : b;
      float keep = bit ? b : a;
      vals[q] = keep + __shfl_xor(send, 1 << step);
    }
  }
  vals[0] += __shfl_xor(vals[0], 8);
  vals[0] += __shfl_xor(vals[0], 16);
  vals[0] += __shfl_xor(vals[0], 32);
}

__device__ __forceinline__ float2 cmul(float2 a, float2 b) {
  return make_float2(a.x*b.x - a.y*b.y, a.x*b.y + a.y*b.x);
}
__device__ __forceinline__ float2 cadd(float2 a, float2 b) {
  return make_float2(a.x + b.x, a.y + b.y);
}
__device__ __forceinline__ float2 csub(float2 a, float2 b) {
  return make_float2(a.x - b.x, a.y - b.y);
}
__device__ __forceinline__ float2 cdiv(float2 a, float2 b) {
  float s = 1.0f / (b.x*b.x + b.y*b.y);
  return make_float2((a.x*b.x + a.y*b.y)*s, (a.y*b.x - a.x*b.y)*s);
}

// ---------------- transpose X -> Xq[i][j]=(re0,im0,re1,im1), + init T/V/W ----
// T: [n][i][k]
// V: plane-split [n][p][j] float4 (p = k-quad: k = p*4+c) — dense lane access
// W: [i][n][m][c]
__global__ __launch_bounds__(256) void k_tr_init(
    const float* __restrict__ X, float4* __restrict__ Xq,
    const float* __restrict__ T0, const float* __restrict__ V0,
    float* __restrict__ T, float* __restrict__ V, float* __restrict__ W)
{
  const int tx = threadIdx.x, ty = threadIdx.y;  // (32, 8)
  const int lt = ty * 32 + tx;
  const int bid = blockIdx.y * 33 + blockIdx.x;
  int t = bid * 256 + lt;
  if (t < 2 * K_B * J_DIM) {               // V: 32768, [n][p][j][c]
    int n = t >> 14;
    int r = t & 16383;
    int p = r >> 13;
    int r2 = r & 8191;
    int j = r2 >> 2, c = r2 & 3;
    int k = p * 4 + c;
    V[t] = V0[(k * J_DIM + j) * 2 + n];
  }
  if (t < 2 * I_DIM * K_B) {               // T: 16400
    int n = t / (I_DIM * K_B);
    int r = t % (I_DIM * K_B);
    int i = r / K_B, k = r % K_B;
    T[t] = T0[(i * K_B + k) * 2 + n];
  }
  if (t < I_DIM * 8) {                     // W: 8200
    int u = t & 7;
    int c = u & 1, m = (u >> 1) & 1, n = u >> 2;
    W[t] = (n == m && c == 0) ? 1.0f : 0.0f;
  }
  // ---- transpose ----
  __shared__ float t0r[32][33], t0i[32][33], t1r[32][33], t1i[32][33];
  const int i0 = blockIdx.x * 32, j0 = blockIdx.y * 32;
  const float2* __restrict__ X2 = (const float2*)X;
  #pragma unroll
  for (int jj = 0; jj < 4; ++jj) {
    int jl = ty + jj * 8;
    int i = i0 + tx;
    if (i < I_DIM) {
      float2 v0 = X2[(size_t)(0 * J_DIM + j0 + jl) * I_DIM + i];
      float2 v1 = X2[(size_t)(1 * J_DIM + j0 + jl) * I_DIM + i];
      t0r[jl][tx] = v0.x; t0i[jl][tx] = v0.y;
      t1r[jl][tx] = v1.x; t1i[jl][tx] = v1.y;
    }
  }
  __syncthreads();
  #pragma unroll
  for (int ii = 0; ii < 4; ++ii) {
    int il = ty + ii * 8;
    int i = i0 + il;
    if (i < I_DIM) {
      Xq[(size_t)i * J_DIM + j0 + tx] =
        make_float4(t0r[tx][il], t0i[tx][il], t1r[tx][il], t1i[tx][il]);
    }
  }
}

// ---------------- NMF T-step body ---------------------------------------------
// V4 planes: source N at offsets (N*2+0)*J_DIM and (N*2+1)*J_DIM (float4 units)
template<int N>
__device__ __forceinline__ void nmfT_src(
    int i, int tid,
    const float4* __restrict__ Xq, float* __restrict__ T,
    const float4* __restrict__ V4, const float* __restrict__ W,
    float* __restrict__ YdR)
{
  float4 xs[8];
  #pragma unroll
  for (int u = 0; u < 8; ++u) xs[u] = Xq[(size_t)i * J_DIM + u * 256 + tid];

  const float4 w = ((const float4*)W)[i * 2 + N];
  const int trow = (N * I_DIM + i) * K_B;
  float t[K_B];
  #pragma unroll
  for (int k = 0; k < K_B; ++k) t[k] = T[trow + k];

  float num[K_B], den[K_B];
  #pragma unroll
  for (int k = 0; k < K_B; ++k) { num[k] = 0.f; den[k] = 0.f; }

  #pragma unroll
  for (int u = 0; u < 8; ++u) {
    int j = u * 256 + tid;
    float4 va = V4[(N * 2 + 0) * J_DIM + j];   // dense: 16 B/lane contiguous
    float4 vb = V4[(N * 2 + 1) * J_DIM + j];
    float v[K_B] = {va.x, va.y, va.z, va.w, vb.x, vb.y, vb.z, vb.w};
    float rn = 0.f;
    #pragma unroll
    for (int k = 0; k < K_B; ++k) rn += t[k] * v[k];
    float4 x = xs[u];
    float yr = w.x * x.x - w.y * x.y + w.z * x.z - w.w * x.w;
    float yi = w.x * x.y + w.y * x.x + w.z * x.w + w.w * x.z;
    float rd = __builtin_amdgcn_rcpf(fabsf(rn) + EPSF);
    float ydr = (yr * yr + yi * yi) * rd * rd;
    YdR[(size_t)i * J_DIM + j] = ydr;
    #pragma unroll
    for (int k = 0; k < K_B; ++k) { num[k] += ydr * v[k]; den[k] += rd * v[k]; }
  }

  float vals[16];
  #pragma unroll
  for (int k = 0; k < K_B; ++k) { vals[k] = num[k]; vals[K_B + k] = den[k]; }
  const int wave = tid >> 6, lane = tid & 63;
  foldReduce16(vals, lane);
  __shared__ float redT[4][16];
  if (lane < 16) redT[wave][lane] = vals[0];   // slot l holds value rev4i(l)
  __syncthreads();
  if (tid < K_B) {
    int r = rev4i(tid);
    float nm = redT[0][r] + redT[1][r] + redT[2][r] + redT[3][r];
    float dn = redT[0][r+1] + redT[1][r+1] + redT[2][r+1] + redT[3][r+1];
    T[trow + tid] *= sqrtf(nm / (dn + EPSF));
  }
}

// ---------------- dual 2x2 solve epilogue (one thread) -----------------------
__device__ __forceinline__ void ip_solve_both(
    int i,
    float D000, float p0, float q0, float D110,
    float D001, float p1, float q1, float D111,
    float* __restrict__ W)
{
  float4 w0 = ((const float4*)W)[i * 2 + 0];
  float4 w1 = ((const float4*)W)[i * 2 + 1];
  float2 W00 = make_float2(w0.x, w0.y), W01 = make_float2(w0.z, w0.w);
  float2 W10 = make_float2(w1.x, w1.y), W11 = make_float2(w1.z, w1.w);
  {
    float D00 = D000 + EPSF, D11 = D110 + EPSF;
    float2 D01 = make_float2(p0, q0);
    float2 D10 = make_float2(p0, -q0);
    float2 A00 = cadd(make_float2(W00.x * D00, W00.y * D00), cmul(W01, D10));
    float2 A01 = cadd(cmul(W00, D01), make_float2(W01.x * D11, W01.y * D11));
    float2 A10 = cadd(make_float2(W10.x * D00, W10.y * D00), cmul(W11, D10));
    float2 A11 = cadd(cmul(W10, D01), make_float2(W11.x * D11, W11.y * D11));
    float2 det = csub(cmul(A00, A11), cmul(A01, A10));
    float2 b0 = cdiv(A11, det);
    float2 b1 = cdiv(make_float2(-A10.x, -A10.y), det);
    float2 Db0 = cadd(make_float2(D00 * b0.x, D00 * b0.y), cmul(D01, b1));
    float2 Db1 = cadd(cmul(D10, b0), make_float2(D11 * b1.x, D11 * b1.y));
    float ip = b0.x * Db0.x + b0.y * Db0.y + b1.x * Db1.x + b1.y * Db1.y;
    float inv = 1.0f / sqrtf(ip + EPSF);
    W00 = make_float2(b0.x * inv, -b0.y * inv);
    W01 = make_float2(b1.x * inv, -b1.y * inv);
  }
  {
    float D00 = D001 + EPSF, D11 = D111 + EPSF;
    float2 D01 = make_float2(p1, q1);
    float2 D10 = make_float2(p1, -q1);
    float2 A00 = cadd(make_float2(W00.x * D00, W00.y * D00), cmul(W01, D10));
    float2 A01 = cadd(cmul(W00, D01), make_float2(W01.x * D11, W01.y * D11));
    float2 A10 = cadd(make_float2(W10.x * D00, W10.y * D00), cmul(W11, D10));
    float2 A11 = cadd(cmul(W10, D01), make_float2(W11.x * D11, W11.y * D11));
    float2 det = csub(cmul(A00, A11), cmul(A01, A10));
    float2 b0 = cdiv(make_float2(-A01.x, -A01.y), det);
    float2 b1 = cdiv(A00, det);
    float2 Db0 = cadd(make_float2(D00 * b0.x, D00 * b0.y), cmul(D01, b1));
    float2 Db1 = cadd(cmul(D10, b0), make_float2(D11 * b1.x, D11 * b1.y));
    float ip = b0.x * Db0.x + b0.y * Db0.y + b1.x * Db1.x + b1.y * Db1.y;
    float inv = 1.0f / sqrtf(ip + EPSF);
    W10 = make_float2(b0.x * inv, -b0.y * inv);
    W11 = make_float2(b1.x * inv, -b1.y * inv);
  }
  ((float4*)W)[i * 2 + 0] = make_float4(W00.x, W00.y, W01.x, W01.y);
  ((float4*)W)[i * 2 + 1] = make_float4(W10.x, W10.y, W11.x, W11.y);
}

// ---------------- K1: nmfT(0) | nmfT(1), XCD-paired on same X rows -----------
__global__ __launch_bounds__(256) void k_nmf2(
    const float4* __restrict__ Xq, float* __restrict__ T,
    const float4* __restrict__ V4, const float* __restrict__ W,
    float* __restrict__ Y0, float* __restrict__ Y1)
{
  int b = blockIdx.x;
  int p, pop;
  if (b >= 2048) { p = 1024; pop = b - 2048; }
  else { pop = (b >> 3) & 1; p = ((b >> 4) << 3) | (b & 7); }
  if (pop == 0)
    nmfT_src<0>(p, threadIdx.x, Xq, T, V4, W, Y0);
  else
    nmfT_src<1>(p, threadIdx.x, Xq, T, V4, W, Y1);
}

// ---------------- K2: V partials, both sources (528 blocks) ------------------
// partials: plane-split [c][p][j] float4 — dense writes, dense fin reads
__global__ __launch_bounds__(256) void k_part2(
    const float* __restrict__ T, const float4* __restrict__ V4,
    const float* __restrict__ Y0, const float* __restrict__ Y1,
    float4* __restrict__ Pn0, float4* __restrict__ Pd0,
    float4* __restrict__ Pn1, float4* __restrict__ Pd1)
{
  const int vb = blockIdx.x;
  const int tid = threadIdx.x;
  const int src = vb / 264;
  const int pb = vb % 264;
  const int jb = pb & 7, c = pb >> 3;
  const int i0 = c * 32;
  const int ni = min(32, I_DIM - i0);
  __shared__ float4 sT4[64];
  if (tid < ni * 2)
    sT4[tid] = ((const float4*)(T + (size_t)(src * I_DIM + i0) * K_B))[tid];
  __syncthreads();

  const float* __restrict__ YdR = src ? Y1 : Y0;
  float4* __restrict__ Pn = src ? Pn1 : Pn0;
  float4* __restrict__ Pd = src ? Pd1 : Pd0;
  const int j = jb * 256 + tid;
  float4 va = V4[(src * 2 + 0) * J_DIM + j];
  float4 vb4 = V4[(src * 2 + 1) * J_DIM + j];
  float v[K_B] = {va.x, va.y, va.z, va.w, vb4.x, vb4.y, vb4.z, vb4.w};
  float num[K_B], den[K_B];
  #pragma unroll
  for (int k = 0; k < K_B; ++k) { num[k] = 0.f; den[k] = 0.f; }

  if (ni == 32) {
    #pragma unroll
    for (int g = 0; g < 4; ++g) {
      float yd[8];
      #pragma unroll
      for (int q = 0; q < 8; ++q)
        yd[q] = YdR[(size_t)(i0 + g * 8 + q) * J_DIM + j];
      #pragma unroll
      for (int q = 0; q < 8; ++q) {
        const int ii = g * 8 + q;
        float4 ta = sT4[ii * 2], tb = sT4[ii * 2 + 1];
        float tk[K_B] = {ta.x, ta.y, ta.z, ta.w, tb.x, tb.y, tb.z, tb.w};
        float rn = 0.f;
        #pragma unroll
        for (int k = 0; k < K_B; ++k) rn += tk[k] * v[k];
        float rd2 = __builtin_amdgcn_rcpf(fabsf(rn) + EPSF);
        #pragma unroll
        for (int k = 0; k < K_B; ++k) {
          num[k] += tk[k] * yd[q];
          den[k] += tk[k] * rd2;
        }
      }
    }
  } else {
    for (int ii = 0; ii < ni; ++ii) {
      float ydr = YdR[(size_t)(i0 + ii) * J_DIM + j];
      float4 ta = sT4[ii * 2], tb = sT4[ii * 2 + 1];
      float tk[K_B] = {ta.x, ta.y, ta.z, ta.w, tb.x, tb.y, tb.z, tb.w};
      float rn = 0.f;
      #pragma unroll
      for (int k = 0; k < K_B; ++k) rn += tk[k] * v[k];
      float rd2 = __builtin_amdgcn_rcpf(fabsf(rn) + EPSF);
      #pragma unroll
      for (int k = 0; k < K_B; ++k) {
        num[k] += tk[k] * ydr;
        den[k] += tk[k] * rd2;
      }
    }
  }
  // dense plane writes: [c][p][j]
  Pn[((size_t)c * 2 + 0) * J_DIM + j] = make_float4(num[0], num[1], num[2], num[3]);
  Pn[((size_t)c * 2 + 1) * J_DIM + j] = make_float4(num[4], num[5], num[6], num[7]);
  Pd[((size_t)c * 2 + 0) * J_DIM + j] = make_float4(den[0], den[1], den[2], den[3]);
  Pd[((size_t)c * 2 + 1) * J_DIM + j] = make_float4(den[4], den[5], den[6], den[7]);
}

// ---------------- K3: V finalize, both sources (32 blocks) -------------------
__global__ __launch_bounds__(256) void k_fin2(
    float4* __restrict__ V4,
    const float4* __restrict__ Pn0, const float4* __restrict__ Pd0,
    const float4* __restrict__ Pn1, const float4* __restrict__ Pd1)
{
  const int vb = blockIdx.x;
  const int tid = threadIdx.x;
  const int src = vb >> 4, fb = vb & 15;
  const float4* __restrict__ Pn = src ? Pn1 : Pn0;
  const float4* __restrict__ Pd = src ? Pd1 : Pd0;
  const int t4 = fb * 256 + tid;   // intra-source element: p*2048 + j, 4096 total
  float4 nm = make_float4(0.f, 0.f, 0.f, 0.f);
  float4 dn = make_float4(0.f, 0.f, 0.f, 0.f);
  #pragma unroll
  for (int c = 0; c < IC; ++c) {
    float4 a = Pn[(size_t)c * 4096 + t4];
    float4 bb = Pd[(size_t)c * 4096 + t4];
    nm.x += a.x; nm.y += a.y; nm.z += a.z; nm.w += a.w;
    dn.x += bb.x; dn.y += bb.y; dn.z += bb.z; dn.w += bb.w;
  }
  float4 v = V4[src * 4096 + t4];
  v.x *= sqrtf(nm.x / (dn.x + EPSF));
  v.y *= sqrtf(nm.y / (dn.y + EPSF));
  v.z *= sqrtf(nm.z / (dn.z + EPSF));
  v.w *= sqrtf(nm.w / (dn.w + EPSF));
  V4[src * 4096 + t4] = v;
}

// ---------------- K4: ipBoth — one X pass, both D's, sequential solves -------
__global__ __launch_bounds__(256) void k_ip2(
    const float4* __restrict__ Xq, const float* __restrict__ T,
    const float4* __restrict__ V4, float* __restrict__ W)
{
  const int i = blockIdx.x;
  const int tid = threadIdx.x;
  float4 xs[8];
  #pragma unroll
  for (int u = 0; u < 8; ++u) xs[u] = Xq[(size_t)i * J_DIM + u * 256 + tid];

  float t0[K_B], t1[K_B];
  #pragma unroll
  for (int k = 0; k < K_B; ++k) {
    t0[k] = T[(0 * I_DIM + i) * K_B + k];
    t1[k] = T[(1 * I_DIM + i) * K_B + k];
  }
  float acc[8];
  #pragma unroll
  for (int q = 0; q < 8; ++q) acc[q] = 0.f;

  #pragma unroll
  for (int u = 0; u < 8; ++u) {
    int j = u * 256 + tid;
    float4 va0 = V4[0 * J_DIM + j];          // n=0 p=0
    float4 vb0 = V4[1 * J_DIM + j];          // n=0 p=1
    float4 va1 = V4[2 * J_DIM + j];          // n=1 p=0
    float4 vb1 = V4[3 * J_DIM + j];          // n=1 p=1
    float rn0 = t0[0]*va0.x + t0[1]*va0.y + t0[2]*va0.z + t0[3]*va0.w
              + t0[4]*vb0.x + t0[5]*vb0.y + t0[6]*vb0.z + t0[7]*vb0.w;
    float rn1 = t1[0]*va1.x + t1[1]*va1.y + t1[2]*va1.z + t1[3]*va1.w
              + t1[4]*vb1.x + t1[5]*vb1.y + t1[6]*vb1.z + t1[7]*vb1.w;
    float w0 = __builtin_amdgcn_rcpf(rn0 + EPSF);
    float w1 = __builtin_amdgcn_rcpf(rn1 + EPSF);
    float4 x = xs[u];
    float m00 = x.x * x.x + x.y * x.y;
    float m11 = x.z * x.z + x.w * x.w;
    float m01r = x.x * x.z + x.y * x.w;
    float m01i = x.y * x.z - x.x * x.w;
    acc[0] += m00 * w0; acc[1] += m01r * w0; acc[2] += m01i * w0; acc[3] += m11 * w0;
    acc[4] += m00 * w1; acc[5] += m01r * w1; acc[6] += m01i * w1; acc[7] += m11 * w1;
  }
  const int wave = tid >> 6, lane = tid & 63;
  foldReduce8(acc, lane);
  __shared__ float redI[4][8];
  if (lane < 8) redI[wave][lane] = acc[0];
  __syncthreads();
  if (tid == 0) {
    const float invJ = 1.0f / (float)J_DIM;
    float s[8];
    #pragma unroll
    for (int vv = 0; vv < 8; ++vv) {
      int r = rev3i(vv);
      s[vv] = (redI[0][r] + redI[1][r] + redI[2][r] + redI[3][r]) * invJ;
    }
    ip_solve_both(i, s[0], s[1], s[2], s[3], s[4], s[5], s[6], s[7], W);
  }
}

// ---------------- output: Y = W @ Xc, layout (N, J, I, 2) --------------------
__global__ __launch_bounds__(256) void k_out(
    const float* __restrict__ X, const float* __restrict__ W, float* __restrict__ out)
{
  const int j = blockIdx.x;
  const int i = blockIdx.y * 256 + threadIdx.x;
  if (i >= I_DIM) return;
  const float2* __restrict__ X2 = (const float2*)X;
  float2 x0 = X2[(size_t)(0 * J_DIM + j) * I_DIM + i];
  float2 x1 = X2[(size_t)(1 * J_DIM + j) * I_DIM + i];
  const float4* __restrict__ W4 = (const float4*)W;
  float4 w0 = W4[i * 2 + 0];
  float4 w1 = W4[i * 2 + 1];
  float2* __restrict__ O = (float2*)out;
  float yr = w0.x * x0.x - w0.y * x0.y + w0.z * x1.x - w0.w * x1.y;
  float yi = w0.x * x0.y + w0.y * x0.x + w0.z * x1.y + w0.w * x1.x;
  O[(size_t)(0 * J_DIM + j) * I_DIM + i] = make_float2(yr, yi);
  yr = w1.x * x0.x - w1.y * x0.y + w1.z * x1.x - w1.w * x1.y;
  yi = w1.x * x0.y + w1.y * x0.x + w1.z * x1.y + w1.w * x1.x;
  O[(size_t)(1 * J_DIM + j) * I_DIM + i] = make_float2(yr, yi);
}

// ---------------- launch ----------------
extern "C" void kernel_launch(void* const* d_in, const int* in_sizes, int n_in,
                              void* d_out, int out_size, void* d_ws, size_t ws_size,
                              hipStream_t stream) {
  const float* X  = (const float*)d_in[0];   // (2, 2048, 1025, 2)
  const float* T0 = (const float*)d_in[1];   // (1025, 8, 2)
  const float* V0 = (const float*)d_in[2];   // (8, 2048, 2)
  float* ws = (float*)d_ws;
  // workspace layout (floats)
  float4* Xq  = (float4*)ws;           // 8396800 floats
  float* Y0   = ws + 8396800;          // 2099200
  float* Y1   = ws + 10496000;         // 2099200
  float* T    = ws + 12595200;         // 16400
  float* V    = ws + 12611600;         // 32768 (plane-split [n][p][j][c])
  float* W    = ws + 12644368;         // 8200
  float4* Pn0 = (float4*)(ws + 12652568);   // 33*2*2048 float4 = 540672 floats
  float4* Pd0 = (float4*)(ws + 13193240);   // 540672
  float4* Pn1 = (float4*)(ws + 13733912);   // 540672
  float4* Pd1 = (float4*)(ws + 14274584);   // 540672
  float4* V4  = (float4*)V;
  float* outp = (float*)d_out;

  k_tr_init<<<dim3(33, 64), dim3(32, 8), 0, stream>>>(X, Xq, T0, V0, T, V, W);
  for (int it = 0; it < 5; ++it) {
    k_nmf2<<<2 * I_DIM, 256, 0, stream>>>(Xq, T, V4, W, Y0, Y1);
    k_part2<<<528, 256, 0, stream>>>(T, V4, Y0, Y1, Pn0, Pd0, Pn1, Pd1);
    k_fin2<<<32, 256, 0, stream>>>(V4, Pn0, Pd0, Pn1, Pd1);
    k_ip2<<<I_DIM, 256, 0, stream>>>(Xq, T, V4, W);
  }
  k_out<<<dim3(J_DIM, 5), 256, 0, stream>>>(X, W, outp);
}

// Round 13
// 275.111 us; speedup vs baseline: 3.3788x; 1.0062x over previous
//
#include <hip/hip_runtime.h>

#define I_DIM 1025
#define J_DIM 2048
#define K_B 8
#define IC 33            // i-chunks of 32 (last has 1)
#define EPSF 1e-20f

// ---------------- helpers ----------------

__device__ __forceinline__ int rev4i(int x) {
  return ((x & 1) << 3) | ((x & 2) << 1) | ((x & 4) >> 1) | ((x & 8) >> 3);
}
__device__ __forceinline__ int rev3i(int x) {
  return ((x & 1) << 2) | (x & 2) | ((x & 4) >> 2);
}

// bf16 round-to-nearest-even pack/unpack (fp32 range preserved)
__device__ __forceinline__ unsigned short f2bf(float f) {
  unsigned u = __float_as_uint(f);
  unsigned r = (u + 0x7FFFu + ((u >> 16) & 1u)) >> 16;
  return (unsigned short)r;
}
__device__ __forceinline__ float bf2f(unsigned short h) {
  return __uint_as_float(((unsigned)h) << 16);
}

// value-halving butterfly: 16 vals over 64 lanes in 17 shuffles.
// Post: vals[0] of lane l (l<16) holds total of value rev4i(l).
__device__ __forceinline__ void foldReduce16(float* vals, int lane) {
  #pragma unroll
  for (int step = 0; step < 4; ++step) {
    const int nv = 8 >> step;           // 8,4,2,1
    const int bit = (lane >> step) & 1;
    #pragma unroll
    for (int q = 0; q < nv; ++q) {
      float a = vals[q], b = vals[q + nv];
      float send = bit ? a : b;
      float keep = bit ? b : a;
      vals[q] = keep + __shfl_xor(send, 1 << step);
    }
  }
  vals[0] += __shfl_xor(vals[0], 16);
  vals[0] += __shfl_xor(vals[0], 32);
}

// 8 vals over 64 lanes. Post: lane l (l<8) holds total of value rev3i(l).
__device__ __forceinline__ void foldReduce8(float* vals, int lane) {
  #pragma unroll
  for (int step = 0; step < 3; ++step) {
    const int nv = 4 >> step;           // 4,2,1
    const int bit = (lane >> step) & 1;
    #pragma unroll
    for (int q = 0; q < nv; ++q) {
      float a = vals[q], b = vals[q + nv];
      float send = bit ? a : b;
      float keep = bit ? b : a;
      vals[q] = keep + __shfl_xor(send, 1 << step);
    }
  }
  vals[0] += __shfl_xor(vals[0], 8);
  vals[0] += __shfl_xor(vals[0], 16);
  vals[0] += __shfl_xor(vals[0], 32);
}

__device__ __forceinline__ float2 cmul(float2 a, float2 b) {
  return make_float2(a.x*b.x - a.y*b.y, a.x*b.y + a.y*b.x);
}
__device__ __forceinline__ float2 cadd(float2 a, float2 b) {
  return make_float2(a.x + b.x, a.y + b.y);
}
__device__ __forceinline__ float2 csub(float2 a, float2 b) {
  return make_float2(a.x - b.x, a.y - b.y);
}
__device__ __forceinline__ float2 cdiv(float2 a, float2 b) {
  float s = 1.0f / (b.x*b.x + b.y*b.y);
  return make_float2((a.x*b.x + a.y*b.y)*s, (a.y*b.x - a.x*b.y)*s);
}

// ---------------- transpose X -> Xq[i][j]=(re0,im0,re1,im1), + init T/V/W ----
// T: [n][i][k]
// V: plane-split [n][p][j] float4 (p = k-quad: k = p*4+c) — dense lane access
// W: [i][n][m][c]
__global__ __launch_bounds__(256) void k_tr_init(
    const float* __restrict__ X, float4* __restrict__ Xq,
    const float* __restrict__ T0, const float* __restrict__ V0,
    float* __restrict__ T, float* __restrict__ V, float* __restrict__ W)
{
  const int tx = threadIdx.x, ty = threadIdx.y;  // (32, 8)
  const int lt = ty * 32 + tx;
  const int bid = blockIdx.y * 33 + blockIdx.x;
  int t = bid * 256 + lt;
  if (t < 2 * K_B * J_DIM) {               // V: 32768, [n][p][j][c]
    int n = t >> 14;
    int r = t & 16383;
    int p = r >> 13;
    int r2 = r & 8191;
    int j = r2 >> 2, c = r2 & 3;
    int k = p * 4 + c;
    V[t] = V0[(k * J_DIM + j) * 2 + n];
  }
  if (t < 2 * I_DIM * K_B) {               // T: 16400
    int n = t / (I_DIM * K_B);
    int r = t % (I_DIM * K_B);
    int i = r / K_B, k = r % K_B;
    T[t] = T0[(i * K_B + k) * 2 + n];
  }
  if (t < I_DIM * 8) {                     // W: 8200
    int u = t & 7;
    int c = u & 1, m = (u >> 1) & 1, n = u >> 2;
    W[t] = (n == m && c == 0) ? 1.0f : 0.0f;
  }
  // ---- transpose ----
  __shared__ float t0r[32][33], t0i[32][33], t1r[32][33], t1i[32][33];
  const int i0 = blockIdx.x * 32, j0 = blockIdx.y * 32;
  const float2* __restrict__ X2 = (const float2*)X;
  #pragma unroll
  for (int jj = 0; jj < 4; ++jj) {
    int jl = ty + jj * 8;
    int i = i0 + tx;
    if (i < I_DIM) {
      float2 v0 = X2[(size_t)(0 * J_DIM + j0 + jl) * I_DIM + i];
      float2 v1 = X2[(size_t)(1 * J_DIM + j0 + jl) * I_DIM + i];
      t0r[jl][tx] = v0.x; t0i[jl][tx] = v0.y;
      t1r[jl][tx] = v1.x; t1i[jl][tx] = v1.y;
    }
  }
  __syncthreads();
  #pragma unroll
  for (int ii = 0; ii < 4; ++ii) {
    int il = ty + ii * 8;
    int i = i0 + il;
    if (i < I_DIM) {
      Xq[(size_t)i * J_DIM + j0 + tx] =
        make_float4(t0r[tx][il], t0i[tx][il], t1r[tx][il], t1i[tx][il]);
    }
  }
}

// ---------------- NMF T-step body ---------------------------------------------
// V4 planes: source N at offsets (N*2+0)*J_DIM and (N*2+1)*J_DIM (float4 units)
// YdR stored bf16 (pure intermediate)
template<int N>
__device__ __forceinline__ void nmfT_src(
    int i, int tid,
    const float4* __restrict__ Xq, float* __restrict__ T,
    const float4* __restrict__ V4, const float* __restrict__ W,
    unsigned short* __restrict__ YdR)
{
  float4 xs[8];
  #pragma unroll
  for (int u = 0; u < 8; ++u) xs[u] = Xq[(size_t)i * J_DIM + u * 256 + tid];

  const float4 w = ((const float4*)W)[i * 2 + N];
  const int trow = (N * I_DIM + i) * K_B;
  float t[K_B];
  #pragma unroll
  for (int k = 0; k < K_B; ++k) t[k] = T[trow + k];

  float num[K_B], den[K_B];
  #pragma unroll
  for (int k = 0; k < K_B; ++k) { num[k] = 0.f; den[k] = 0.f; }

  #pragma unroll
  for (int h = 0; h < 2; ++h) {
    // hoist V loads for 4 j-groups: 8 independent loads in flight
    float4 va[4], vb[4];
    #pragma unroll
    for (int q = 0; q < 4; ++q) {
      int j = (h * 4 + q) * 256 + tid;
      va[q] = V4[(N * 2 + 0) * J_DIM + j];
      vb[q] = V4[(N * 2 + 1) * J_DIM + j];
    }
    #pragma unroll
    for (int q = 0; q < 4; ++q) {
      int u = h * 4 + q;
      int j = u * 256 + tid;
      float v[K_B] = {va[q].x, va[q].y, va[q].z, va[q].w,
                      vb[q].x, vb[q].y, vb[q].z, vb[q].w};
      float rn = 0.f;
      #pragma unroll
      for (int k = 0; k < K_B; ++k) rn += t[k] * v[k];
      float4 x = xs[u];
      float yr = w.x * x.x - w.y * x.y + w.z * x.z - w.w * x.w;
      float yi = w.x * x.y + w.y * x.x + w.z * x.w + w.w * x.z;
      float rd = __builtin_amdgcn_rcpf(fabsf(rn) + EPSF);
      float ydr = (yr * yr + yi * yi) * rd * rd;
      YdR[(size_t)i * J_DIM + j] = f2bf(ydr);
      float ydq = bf2f(f2bf(ydr));   // accumulate exactly what part2 will read
      #pragma unroll
      for (int k = 0; k < K_B; ++k) { num[k] += ydq * v[k]; den[k] += rd * v[k]; }
    }
  }

  float vals[16];
  #pragma unroll
  for (int k = 0; k < K_B; ++k) { vals[k] = num[k]; vals[K_B + k] = den[k]; }
  const int wave = tid >> 6, lane = tid & 63;
  foldReduce16(vals, lane);
  __shared__ float redT[4][16];
  if (lane < 16) redT[wave][lane] = vals[0];   // slot l holds value rev4i(l)
  __syncthreads();
  if (tid < K_B) {
    int r = rev4i(tid);
    float nm = redT[0][r] + redT[1][r] + redT[2][r] + redT[3][r];
    float dn = redT[0][r+1] + redT[1][r+1] + redT[2][r+1] + redT[3][r+1];
    T[trow + tid] *= sqrtf(nm / (dn + EPSF));
  }
}

// ---------------- dual 2x2 solve epilogue (one thread) -----------------------
__device__ __forceinline__ void ip_solve_both(
    int i,
    float D000, float p0, float q0, float D110,
    float D001, float p1, float q1, float D111,
    float* __restrict__ W)
{
  float4 w0 = ((const float4*)W)[i * 2 + 0];
  float4 w1 = ((const float4*)W)[i * 2 + 1];
  float2 W00 = make_float2(w0.x, w0.y), W01 = make_float2(w0.z, w0.w);
  float2 W10 = make_float2(w1.x, w1.y), W11 = make_float2(w1.z, w1.w);
  {
    float D00 = D000 + EPSF, D11 = D110 + EPSF;
    float2 D01 = make_float2(p0, q0);
    float2 D10 = make_float2(p0, -q0);
    float2 A00 = cadd(make_float2(W00.x * D00, W00.y * D00), cmul(W01, D10));
    float2 A01 = cadd(cmul(W00, D01), make_float2(W01.x * D11, W01.y * D11));
    float2 A10 = cadd(make_float2(W10.x * D00, W10.y * D00), cmul(W11, D10));
    float2 A11 = cadd(cmul(W10, D01), make_float2(W11.x * D11, W11.y * D11));
    float2 det = csub(cmul(A00, A11), cmul(A01, A10));
    float2 b0 = cdiv(A11, det);
    float2 b1 = cdiv(make_float2(-A10.x, -A10.y), det);
    float2 Db0 = cadd(make_float2(D00 * b0.x, D00 * b0.y), cmul(D01, b1));
    float2 Db1 = cadd(cmul(D10, b0), make_float2(D11 * b1.x, D11 * b1.y));
    float ip = b0.x * Db0.x + b0.y * Db0.y + b1.x * Db1.x + b1.y * Db1.y;
    float inv = 1.0f / sqrtf(ip + EPSF);
    W00 = make_float2(b0.x * inv, -b0.y * inv);
    W01 = make_float2(b1.x * inv, -b1.y * inv);
  }
  {
    float D00 = D001 + EPSF, D11 = D111 + EPSF;
    float2 D01 = make_float2(p1, q1);
    float2 D10 = make_float2(p1, -q1);
    float2 A00 = cadd(make_float2(W00.x * D00, W00.y * D00), cmul(W01, D10));
    float2 A01 = cadd(cmul(W00, D01), make_float2(W01.x * D11, W01.y * D11));
    float2 A10 = cadd(make_float2(W10.x * D00, W10.y * D00), cmul(W11, D10));
    float2 A11 = cadd(cmul(W10, D01), make_float2(W11.x * D11, W11.y * D11));
    float2 det = csub(cmul(A00, A11), cmul(A01, A10));
    float2 b0 = cdiv(make_float2(-A01.x, -A01.y), det);
    float2 b1 = cdiv(A00, det);
    float2 Db0 = cadd(make_float2(D00 * b0.x, D00 * b0.y), cmul(D01, b1));
    float2 Db1 = cadd(cmul(D10, b0), make_float2(D11 * b1.x, D11 * b1.y));
    float ip = b0.x * Db0.x + b0.y * Db0.y + b1.x * Db1.x + b1.y * Db1.y;
    float inv = 1.0f / sqrtf(ip + EPSF);
    W10 = make_float2(b0.x * inv, -b0.y * inv);
    W11 = make_float2(b1.x * inv, -b1.y * inv);
  }
  ((float4*)W)[i * 2 + 0] = make_float4(W00.x, W00.y, W01.x, W01.y);
  ((float4*)W)[i * 2 + 1] = make_float4(W10.x, W10.y, W11.x, W11.y);
}

// ---------------- K1: nmfT(0) | nmfT(1), XCD-paired on same X rows -----------
__global__ __launch_bounds__(256) void k_nmf2(
    const float4* __restrict__ Xq, float* __restrict__ T,
    const float4* __restrict__ V4, const float* __restrict__ W,
    unsigned short* __restrict__ Y0, unsigned short* __restrict__ Y1)
{
  int b = blockIdx.x;
  int p, pop;
  if (b >= 2048) { p = 1024; pop = b - 2048; }
  else { pop = (b >> 3) & 1; p = ((b >> 4) << 3) | (b & 7); }
  if (pop == 0)
    nmfT_src<0>(p, threadIdx.x, Xq, T, V4, W, Y0);
  else
    nmfT_src<1>(p, threadIdx.x, Xq, T, V4, W, Y1);
}

// ---------------- K2: V partials, both sources (528 blocks) ------------------
// partials: plane-split [c][p][j] float4 — dense writes, dense fin reads
__global__ __launch_bounds__(256) void k_part2(
    const float* __restrict__ T, const float4* __restrict__ V4,
    const unsigned short* __restrict__ Y0, const unsigned short* __restrict__ Y1,
    float4* __restrict__ Pn0, float4* __restrict__ Pd0,
    float4* __restrict__ Pn1, float4* __restrict__ Pd1)
{
  const int vb = blockIdx.x;
  const int tid = threadIdx.x;
  const int src = vb / 264;
  const int pb = vb % 264;
  const int jb = pb & 7, c = pb >> 3;
  const int i0 = c * 32;
  const int ni = min(32, I_DIM - i0);
  __shared__ float4 sT4[64];
  if (tid < ni * 2)
    sT4[tid] = ((const float4*)(T + (size_t)(src * I_DIM + i0) * K_B))[tid];
  __syncthreads();

  const unsigned short* __restrict__ YdR = src ? Y1 : Y0;
  float4* __restrict__ Pn = src ? Pn1 : Pn0;
  float4* __restrict__ Pd = src ? Pd1 : Pd0;
  const int j = jb * 256 + tid;
  float4 va = V4[(src * 2 + 0) * J_DIM + j];
  float4 vb4 = V4[(src * 2 + 1) * J_DIM + j];
  float v[K_B] = {va.x, va.y, va.z, va.w, vb4.x, vb4.y, vb4.z, vb4.w};
  float num[K_B], den[K_B];
  #pragma unroll
  for (int k = 0; k < K_B; ++k) { num[k] = 0.f; den[k] = 0.f; }

  if (ni == 32) {
    #pragma unroll
    for (int g = 0; g < 4; ++g) {
      unsigned short yd[8];
      #pragma unroll
      for (int q = 0; q < 8; ++q)
        yd[q] = YdR[(size_t)(i0 + g * 8 + q) * J_DIM + j];
      #pragma unroll
      for (int q = 0; q < 8; ++q) {
        const int ii = g * 8 + q;
        float ydr = bf2f(yd[q]);
        float4 ta = sT4[ii * 2], tb = sT4[ii * 2 + 1];
        float tk[K_B] = {ta.x, ta.y, ta.z, ta.w, tb.x, tb.y, tb.z, tb.w};
        float rn = 0.f;
        #pragma unroll
        for (int k = 0; k < K_B; ++k) rn += tk[k] * v[k];
        float rd2 = __builtin_amdgcn_rcpf(fabsf(rn) + EPSF);
        #pragma unroll
        for (int k = 0; k < K_B; ++k) {
          num[k] += tk[k] * ydr;
          den[k] += tk[k] * rd2;
        }
      }
    }
  } else {
    for (int ii = 0; ii < ni; ++ii) {
      float ydr = bf2f(YdR[(size_t)(i0 + ii) * J_DIM + j]);
      float4 ta = sT4[ii * 2], tb = sT4[ii * 2 + 1];
      float tk[K_B] = {ta.x, ta.y, ta.z, ta.w, tb.x, tb.y, tb.z, tb.w};
      float rn = 0.f;
      #pragma unroll
      for (int k = 0; k < K_B; ++k) rn += tk[k] * v[k];
      float rd2 = __builtin_amdgcn_rcpf(fabsf(rn) + EPSF);
      #pragma unroll
      for (int k = 0; k < K_B; ++k) {
        num[k] += tk[k] * ydr;
        den[k] += tk[k] * rd2;
      }
    }
  }
  // dense plane writes: [c][p][j]
  Pn[((size_t)c * 2 + 0) * J_DIM + j] = make_float4(num[0], num[1], num[2], num[3]);
  Pn[((size_t)c * 2 + 1) * J_DIM + j] = make_float4(num[4], num[5], num[6], num[7]);
  Pd[((size_t)c * 2 + 0) * J_DIM + j] = make_float4(den[0], den[1], den[2], den[3]);
  Pd[((size_t)c * 2 + 1) * J_DIM + j] = make_float4(den[4], den[5], den[6], den[7]);
}

// ---------------- K3: V finalize, both sources (32 blocks) -------------------
__global__ __launch_bounds__(256) void k_fin2(
    float4* __restrict__ V4,
    const float4* __restrict__ Pn0, const float4* __restrict__ Pd0,
    const float4* __restrict__ Pn1, const float4* __restrict__ Pd1)
{
  const int vb = blockIdx.x;
  const int tid = threadIdx.x;
  const int src = vb >> 4, fb = vb & 15;
  const float4* __restrict__ Pn = src ? Pn1 : Pn0;
  const float4* __restrict__ Pd = src ? Pd1 : Pd0;
  const int t4 = fb * 256 + tid;   // intra-source element: p*2048 + j, 4096 total
  float4 nm = make_float4(0.f, 0.f, 0.f, 0.f);
  float4 dn = make_float4(0.f, 0.f, 0.f, 0.f);
  #pragma unroll
  for (int c = 0; c < IC; ++c) {
    float4 a = Pn[(size_t)c * 4096 + t4];
    float4 bb = Pd[(size_t)c * 4096 + t4];
    nm.x += a.x; nm.y += a.y; nm.z += a.z; nm.w += a.w;
    dn.x += bb.x; dn.y += bb.y; dn.z += bb.z; dn.w += bb.w;
  }
  float4 v = V4[src * 4096 + t4];
  v.x *= sqrtf(nm.x / (dn.x + EPSF));
  v.y *= sqrtf(nm.y / (dn.y + EPSF));
  v.z *= sqrtf(nm.z / (dn.z + EPSF));
  v.w *= sqrtf(nm.w / (dn.w + EPSF));
  V4[src * 4096 + t4] = v;
}

// ---------------- K4: ipBoth — one X pass, both D's, sequential solves -------
__global__ __launch_bounds__(256) void k_ip2(
    const float4* __restrict__ Xq, const float* __restrict__ T,
    const float4* __restrict__ V4, float* __restrict__ W)
{
  const int i = blockIdx.x;
  const int tid = threadIdx.x;
  float4 xs[8];
  #pragma unroll
  for (int u = 0; u < 8; ++u) xs[u] = Xq[(size_t)i * J_DIM + u * 256 + tid];

  float t0[K_B], t1[K_B];
  #pragma unroll
  for (int k = 0; k < K_B; ++k) {
    t0[k] = T[(0 * I_DIM + i) * K_B + k];
    t1[k] = T[(1 * I_DIM + i) * K_B + k];
  }
  float acc[8];
  #pragma unroll
  for (int q = 0; q < 8; ++q) acc[q] = 0.f;

  #pragma unroll
  for (int h = 0; h < 2; ++h) {
    // hoist V loads for 4 j-groups: 16 independent loads in flight
    float4 va0[4], vb0[4], va1[4], vb1[4];
    #pragma unroll
    for (int q = 0; q < 4; ++q) {
      int j = (h * 4 + q) * 256 + tid;
      va0[q] = V4[0 * J_DIM + j];
      vb0[q] = V4[1 * J_DIM + j];
      va1[q] = V4[2 * J_DIM + j];
      vb1[q] = V4[3 * J_DIM + j];
    }
    #pragma unroll
    for (int q = 0; q < 4; ++q) {
      int u = h * 4 + q;
      float rn0 = t0[0]*va0[q].x + t0[1]*va0[q].y + t0[2]*va0[q].z + t0[3]*va0[q].w
                + t0[4]*vb0[q].x + t0[5]*vb0[q].y + t0[6]*vb0[q].z + t0[7]*vb0[q].w;
      float rn1 = t1[0]*va1[q].x + t1[1]*va1[q].y + t1[2]*va1[q].z + t1[3]*va1[q].w
                + t1[4]*vb1[q].x + t1[5]*vb1[q].y + t1[6]*vb1[q].z + t1[7]*vb1[q].w;
      float w0 = __builtin_amdgcn_rcpf(rn0 + EPSF);
      float w1 = __builtin_amdgcn_rcpf(rn1 + EPSF);
      float4 x = xs[u];
      float m00 = x.x * x.x + x.y * x.y;
      float m11 = x.z * x.z + x.w * x.w;
      float m01r = x.x * x.z + x.y * x.w;
      float m01i = x.y * x.z - x.x * x.w;
      acc[0] += m00 * w0; acc[1] += m01r * w0; acc[2] += m01i * w0; acc[3] += m11 * w0;
      acc[4] += m00 * w1; acc[5] += m01r * w1; acc[6] += m01i * w1; acc[7] += m11 * w1;
    }
  }
  const int wave = tid >> 6, lane = tid & 63;
  foldReduce8(acc, lane);
  __shared__ float redI[4][8];
  if (lane < 8) redI[wave][lane] = acc[0];
  __syncthreads();
  if (tid == 0) {
    const float invJ = 1.0f / (float)J_DIM;
    float s[8];
    #pragma unroll
    for (int vv = 0; vv < 8; ++vv) {
      int r = rev3i(vv);
      s[vv] = (redI[0][r] + redI[1][r] + redI[2][r] + redI[3][r]) * invJ;
    }
    ip_solve_both(i, s[0], s[1], s[2], s[3], s[4], s[5], s[6], s[7], W);
  }
}

// ---------------- output: Y = W @ Xc, layout (N, J, I, 2) --------------------
// grid (2048, 4); plane-0 thread 0 also handles i=1024 (kills 2048 empty blocks)
__global__ __launch_bounds__(256) void k_out(
    const float* __restrict__ X, const float* __restrict__ W, float* __restrict__ out)
{
  const int j = blockIdx.x;
  const int i = blockIdx.y * 256 + threadIdx.x;
  const float2* __restrict__ X2 = (const float2*)X;
  const float4* __restrict__ W4 = (const float4*)W;
  float2* __restrict__ O = (float2*)out;
  {
    float2 x0 = X2[(size_t)(0 * J_DIM + j) * I_DIM + i];
    float2 x1 = X2[(size_t)(1 * J_DIM + j) * I_DIM + i];
    float4 w0 = W4[i * 2 + 0];
    float4 w1 = W4[i * 2 + 1];
    float yr = w0.x * x0.x - w0.y * x0.y + w0.z * x1.x - w0.w * x1.y;
    float yi = w0.x * x0.y + w0.y * x0.x + w0.z * x1.y + w0.w * x1.x;
    O[(size_t)(0 * J_DIM + j) * I_DIM + i] = make_float2(yr, yi);
    yr = w1.x * x0.x - w1.y * x0.y + w1.z * x1.x - w1.w * x1.y;
    yi = w1.x * x0.y + w1.y * x0.x + w1.z * x1.y + w1.w * x1.x;
    O[(size_t)(1 * J_DIM + j) * I_DIM + i] = make_float2(yr, yi);
  }
  if (blockIdx.y == 0 && threadIdx.x == 0) {
    const int il = 1024;
    float2 x0 = X2[(size_t)(0 * J_DIM + j) * I_DIM + il];
    float2 x1 = X2[(size_t)(1 * J_DIM + j) * I_DIM + il];
    float4 w0 = W4[il * 2 + 0];
    float4 w1 = W4[il * 2 + 1];
    float yr = w0.x * x0.x - w0.y * x0.y + w0.z * x1.x - w0.w * x1.y;
    float yi = w0.x * x0.y + w0.y * x0.x + w0.z * x1.y + w0.w * x1.x;
    O[(size_t)(0 * J_DIM + j) * I_DIM + il] = make_float2(yr, yi);
    yr = w1.x * x0.x - w1.y * x0.y + w1.z * x1.x - w1.w * x1.y;
    yi = w1.x * x0.y + w1.y * x0.x + w1.z * x1.y + w1.w * x1.x;
    O[(size_t)(1 * J_DIM + j) * I_DIM + il] = make_float2(yr, yi);
  }
}

// ---------------- launch ----------------
extern "C" void kernel_launch(void* const* d_in, const int* in_sizes, int n_in,
                              void* d_out, int out_size, void* d_ws, size_t ws_size,
                              hipStream_t stream) {
  const float* X  = (const float*)d_in[0];   // (2, 2048, 1025, 2)
  const float* T0 = (const float*)d_in[1];   // (1025, 8, 2)
  const float* V0 = (const float*)d_in[2];   // (8, 2048, 2)
  float* ws = (float*)d_ws;
  // workspace layout (floats)
  float4* Xq  = (float4*)ws;                      // 8396800 floats
  unsigned short* Y0 = (unsigned short*)(ws + 8396800);   // bf16, 2099200 elems
  unsigned short* Y1 = (unsigned short*)(ws + 10496000);  // bf16
  float* T    = ws + 12595200;         // 16400
  float* V    = ws + 12611600;         // 32768 (plane-split [n][p][j][c])
  float* W    = ws + 12644368;         // 8200
  float4* Pn0 = (float4*)(ws + 12652568);   // 33*2*2048 float4 = 540672 floats
  float4* Pd0 = (float4*)(ws + 13193240);   // 540672
  float4* Pn1 = (float4*)(ws + 13733912);   // 540672
  float4* Pd1 = (float4*)(ws + 14274584);   // 540672
  float4* V4  = (float4*)V;
  float* outp = (float*)d_out;

  k_tr_init<<<dim3(33, 64), dim3(32, 8), 0, stream>>>(X, Xq, T0, V0, T, V, W);
  for (int it = 0; it < 5; ++it) {
    k_nmf2<<<2 * I_DIM, 256, 0, stream>>>(Xq, T, V4, W, Y0, Y1);
    k_part2<<<528, 256, 0, stream>>>(T, V4, Y0, Y1, Pn0, Pd0, Pn1, Pd1);
    k_fin2<<<32, 256, 0, stream>>>(V4, Pn0, Pd0, Pn1, Pd1);
    k_ip2<<<I_DIM, 256, 0, stream>>>(Xq, T, V4, W);
  }
  k_out<<<dim3(J_DIM, 4), 256, 0, stream>>>(X, W, outp);
}